// Round 17
// baseline (247.122 us; speedup 1.0000x reference)
//
#include <hip/hip_runtime.h>
#include <hip/hip_bf16.h>

#define SCALE_F 0.125f

typedef __attribute__((ext_vector_type(8))) short short8;
typedef __attribute__((ext_vector_type(4))) float f32x4;
typedef __attribute__((address_space(3))) void lds_void;
typedef const __attribute__((address_space(1))) void glb_void;

__device__ __forceinline__ unsigned short f2b(float f){
  return __builtin_bit_cast(unsigned short, __float2bfloat16(f));
}
__device__ __forceinline__ float b2f(unsigned short h){
  return __uint_as_float((unsigned int)h << 16);
}

// ---------------- sgemm body (bf16x3 split, 64x64 tile, BK=64) -------------
// sm: 16384 ushorts.  MODE 0/2/3: plain/Q-layout/S-layout f32 out.
// MODE 1: K=1024, k>=512 A-rows come from p0+p1.
template<int MODE>
__device__ __forceinline__ void sgemm_body(
    unsigned short* sm, const float* __restrict__ A,
    const float* __restrict__ p0, const float* __restrict__ p1,
    const float* __restrict__ W, const float* __restrict__ bias,
    float* __restrict__ outf, float scale, int m0, int n0, int K, int tid)
{
  unsigned short* Ah = sm;
  unsigned short* Al = sm + 4096;
  unsigned short* Bh = sm + 8192;
  unsigned short* Bl = sm + 12288;
  const int lane = tid & 63, wv = tid >> 6, lr = lane & 15, lg = lane >> 4;

  f32x4 acc[4];
  #pragma unroll
  for (int nf = 0; nf < 4; nf++) acc[nf] = (f32x4){0.f, 0.f, 0.f, 0.f};

  for (int k0 = 0; k0 < K; k0 += 64) {
    float4 a0[2], a1[2];
    float bw[2][8];
    const bool dual = (MODE == 1) && (k0 >= 512);
    const int kk = dual ? (k0 - 512) : k0;
    #pragma unroll
    for (int j = 0; j < 2; j++) {
      int idx = tid + j * 256;
      int row = idx >> 3, c8 = idx & 7;
      size_t base = (size_t)(m0 + row) * 512 + kk + c8 * 8;
      if (dual) {
        float4 x0 = *(const float4*)&p0[base];
        float4 x1 = *(const float4*)&p0[base + 4];
        float4 y0 = *(const float4*)&p1[base];
        float4 y1 = *(const float4*)&p1[base + 4];
        a0[j] = (float4){x0.x + y0.x, x0.y + y0.y, x0.z + y0.z, x0.w + y0.w};
        a1[j] = (float4){x1.x + y1.x, x1.y + y1.y, x1.z + y1.z, x1.w + y1.w};
      } else {
        a0[j] = *(const float4*)&A[base];
        a1[j] = *(const float4*)&A[base + 4];
      }
    }
    #pragma unroll
    for (int j = 0; j < 2; j++) {
      int idx = tid + j * 256;
      int nl = idx >> 3, kseg = idx & 7;
      #pragma unroll
      for (int e = 0; e < 8; e++)
        bw[j][e] = W[(size_t)(k0 + kseg * 8 + e) * 512 + n0 + nl];
    }
    __syncthreads();
    #pragma unroll
    for (int j = 0; j < 2; j++) {
      int idx = tid + j * 256;
      int row = idx >> 3, c8 = idx & 7;
      int off = row * 64 + ((c8 * 8) ^ ((row & 7) << 3));
      float v[8] = {a0[j].x, a0[j].y, a0[j].z, a0[j].w,
                    a1[j].x, a1[j].y, a1[j].z, a1[j].w};
      short8 h, l;
      #pragma unroll
      for (int e = 0; e < 8; e++) {
        unsigned short hh = f2b(v[e]);
        h[e] = (short)hh;
        l[e] = (short)f2b(v[e] - b2f(hh));
      }
      *(short8*)&Ah[off] = h;
      *(short8*)&Al[off] = l;
    }
    #pragma unroll
    for (int j = 0; j < 2; j++) {
      int idx = tid + j * 256;
      int nl = idx >> 3, kseg = idx & 7;
      int off = nl * 64 + ((kseg * 8) ^ ((nl & 7) << 3));
      short8 h, l;
      #pragma unroll
      for (int e = 0; e < 8; e++) {
        unsigned short hh = f2b(bw[j][e]);
        h[e] = (short)hh;
        l[e] = (short)f2b(bw[j][e] - b2f(hh));
      }
      *(short8*)&Bh[off] = h;
      *(short8*)&Bl[off] = l;
    }
    __syncthreads();
    #pragma unroll
    for (int ks = 0; ks < 2; ks++) {
      int rowa = wv * 16 + lr;
      int aoff = rowa * 64 + ((ks * 32 + lg * 8) ^ ((rowa & 7) << 3));
      short8 ah = *(const short8*)&Ah[aoff];
      short8 al = *(const short8*)&Al[aoff];
      #pragma unroll
      for (int nf = 0; nf < 4; nf++) {
        int rowb = nf * 16 + lr;
        int boff = rowb * 64 + ((ks * 32 + lg * 8) ^ ((rowb & 7) << 3));
        short8 bh = *(const short8*)&Bh[boff];
        short8 bl = *(const short8*)&Bl[boff];
        acc[nf] = __builtin_amdgcn_mfma_f32_16x16x32_bf16(ah, bh, acc[nf], 0, 0, 0);
        acc[nf] = __builtin_amdgcn_mfma_f32_16x16x32_bf16(ah, bl, acc[nf], 0, 0, 0);
        acc[nf] = __builtin_amdgcn_mfma_f32_16x16x32_bf16(al, bh, acc[nf], 0, 0, 0);
      }
    }
  }

  #pragma unroll
  for (int nf = 0; nf < 4; nf++) {
    int n = n0 + nf * 16 + lr;
    float bv = bias[n];
    #pragma unroll
    for (int i = 0; i < 4; i++) {
      int m = m0 + wv * 16 + lg * 4 + i;
      float v = (acc[nf][i] + bv) * scale;
      if (MODE == 0 || MODE == 1) {
        outf[(size_t)m * 512 + n] = v;
      } else if (MODE == 2) {
        int bb = m >> 9, qq = m & 511, hh = n >> 6, d = n & 63;
        outf[((((size_t)bb * 8 + hh) * 512 + qq) << 6) + d] = v;
      } else {
        int bb = m >> 5, nn = m & 31, hh = n >> 6, d = n & 63;
        outf[((((size_t)bb * 8 + hh) * 32 + nn) << 6) + d] = v;
      }
    }
  }
}

// -------- proj epilogue (shared by both staging variants) -------------------
template<int VT>
__device__ __forceinline__ void proj_epilogue(
    f32x4 (&acc)[4][4], const float* __restrict__ bias,
    __hip_bfloat16* __restrict__ outW, int m0, int n0,
    int wr, int wc, int lr, int lg)
{
  #pragma unroll
  for (int nj = 0; nj < 4; nj++) {
    int n = n0 + wc * 64 + nj * 16 + lr;
    float bv = bias[n];
    int hh = n >> 6, d = n & 63;
    #pragma unroll
    for (int mi = 0; mi < 4; mi++) {
      if (VT == 0) {
        #pragma unroll
        for (int i = 0; i < 4; i++) {
          int m = m0 + wr * 64 + mi * 16 + lg * 4 + i;
          int bb = m >> 13, r = m & 8191, nn = r >> 8, tt = r & 255;
          outW[(((((size_t)bb * 8 + hh) * 32 + nn) * 256 + tt) << 6) + d] =
              __float2bfloat16(acc[mi][nj][i] + bv);
        }
      } else {
        int m = m0 + wr * 64 + mi * 16 + lg * 4;   // 4 consecutive t
        int bb = m >> 13, r = m & 8191, nn = r >> 8, t0 = r & 255;
        uint2 pk;
        pk.x = (unsigned)f2b(acc[mi][nj][0] + bv) | ((unsigned)f2b(acc[mi][nj][1] + bv) << 16);
        pk.y = (unsigned)f2b(acc[mi][nj][2] + bv) | ((unsigned)f2b(acc[mi][nj][3] + bv) << 16);
        *(uint2*)((unsigned short*)outW +
                  (((((size_t)bb * 8 + hh) * 32 + nn) * 64 + d) << 8) + t0) = pk;
      }
    }
  }
}

// ------------- proj body, reg-staged variant (fallback) --------------------
template<int VT>
__device__ __forceinline__ void proj_reg(
    unsigned short* sm, const float* __restrict__ A,
    const unsigned short* __restrict__ BT, const float* __restrict__ bias,
    __hip_bfloat16* __restrict__ outW, int bidLocal, int tid)
{
  unsigned short* As = sm;
  unsigned short* Bs = sm + 8192;
  const int xcd = bidLocal & 7, local = bidLocal >> 3;
  const int mx = xcd * 32 + (local >> 2);
  const int ny = local & 3;
  const int m0 = mx * 128, n0 = ny * 128;
  const int lane = tid & 63, wv = tid >> 6, lr = lane & 15, lg = lane >> 4;
  const int wr = wv >> 1, wc = wv & 1;

  f32x4 acc[4][4];
  #pragma unroll
  for (int mi = 0; mi < 4; mi++)
    #pragma unroll
    for (int nj = 0; nj < 4; nj++) acc[mi][nj] = (f32x4){0.f, 0.f, 0.f, 0.f};

  for (int k0 = 0; k0 < 512; k0 += 64) {
    float4 a0[4], a1[4]; uint4 bq[4];
    #pragma unroll
    for (int j = 0; j < 4; j++) {
      int idx = tid + j * 256;
      int row = idx >> 3, c8 = idx & 7;
      const float* ap = A + (size_t)(m0 + row) * 512 + k0 + c8 * 8;
      a0[j] = *(const float4*)ap;
      a1[j] = *(const float4*)(ap + 4);
      bq[j] = *(const uint4*)(BT + (size_t)(n0 + row) * 512 + k0 + c8 * 8);
    }
    __syncthreads();
    #pragma unroll
    for (int j = 0; j < 4; j++) {
      int idx = tid + j * 256;
      int row = idx >> 3, c8 = idx & 7;
      int off = row * 64 + ((c8 * 8) ^ ((row & 7) << 3));
      short8 pk;
      pk[0] = (short)f2b(a0[j].x); pk[1] = (short)f2b(a0[j].y);
      pk[2] = (short)f2b(a0[j].z); pk[3] = (short)f2b(a0[j].w);
      pk[4] = (short)f2b(a1[j].x); pk[5] = (short)f2b(a1[j].y);
      pk[6] = (short)f2b(a1[j].z); pk[7] = (short)f2b(a1[j].w);
      *(short8*)&As[off] = pk;
      *(uint4*)&Bs[off] = bq[j];
    }
    __syncthreads();
    #pragma unroll
    for (int ks = 0; ks < 2; ks++) {
      short8 af[4], bfp[4];
      #pragma unroll
      for (int mi = 0; mi < 4; mi++) {
        int row = wr * 64 + mi * 16 + lr;
        af[mi] = *(const short8*)&As[row * 64 + ((ks * 32 + lg * 8) ^ ((row & 7) << 3))];
      }
      #pragma unroll
      for (int nj = 0; nj < 4; nj++) {
        int row = wc * 64 + nj * 16 + lr;
        bfp[nj] = *(const short8*)&Bs[row * 64 + ((ks * 32 + lg * 8) ^ ((row & 7) << 3))];
      }
      #pragma unroll
      for (int mi = 0; mi < 4; mi++)
        #pragma unroll
        for (int nj = 0; nj < 4; nj++)
          acc[mi][nj] = __builtin_amdgcn_mfma_f32_16x16x32_bf16(af[mi], bfp[nj], acc[mi][nj], 0, 0, 0);
    }
  }
  proj_epilogue<VT>(acc, bias, outW, m0, n0, wr, wc, lr, lg);
}

// ------------- proj body, global_load_lds variant ---------------------------
template<int VT>
__device__ __forceinline__ void proj_glds(
    unsigned short* sm, const unsigned short* __restrict__ Abf,
    const unsigned short* __restrict__ BT, const float* __restrict__ bias,
    __hip_bfloat16* __restrict__ outW, int bidLocal, int tid)
{
  unsigned short* As = sm;
  unsigned short* Bs = sm + 8192;
  const int xcd = bidLocal & 7, local = bidLocal >> 3;
  const int mx = xcd * 32 + (local >> 2);
  const int ny = local & 3;
  const int m0 = mx * 128, n0 = ny * 128;
  const int lane = tid & 63, wv = tid >> 6, lr = lane & 15, lg = lane >> 4;
  const int wr = wv >> 1, wc = wv & 1;
  const int srow = tid >> 3, scc = tid & 7;

  f32x4 acc[4][4];
  #pragma unroll
  for (int mi = 0; mi < 4; mi++)
    #pragma unroll
    for (int nj = 0; nj < 4; nj++) acc[mi][nj] = (f32x4){0.f, 0.f, 0.f, 0.f};

  for (int k0 = 0; k0 < 512; k0 += 64) {
    __syncthreads();
    #pragma unroll
    for (int issue = 0; issue < 4; issue++) {
      int row = issue * 32 + srow;
      int cs = (scc ^ (row & 7)) * 8;
      const unsigned short* ga = Abf + (size_t)(m0 + row) * 512 + k0 + cs;
      const unsigned short* gb = BT  + (size_t)(n0 + row) * 512 + k0 + cs;
      unsigned short* la = As + issue * 2048 + wv * 512;
      unsigned short* lb = Bs + issue * 2048 + wv * 512;
      __builtin_amdgcn_global_load_lds((glb_void*)ga, (lds_void*)la, 16, 0, 0);
      __builtin_amdgcn_global_load_lds((glb_void*)gb, (lds_void*)lb, 16, 0, 0);
    }
    asm volatile("s_waitcnt vmcnt(0)" ::: "memory");
    __syncthreads();
    #pragma unroll
    for (int ks = 0; ks < 2; ks++) {
      short8 af[4], bfp[4];
      #pragma unroll
      for (int mi = 0; mi < 4; mi++) {
        int row = wr * 64 + mi * 16 + lr;
        af[mi] = *(const short8*)&As[row * 64 + ((ks * 32 + lg * 8) ^ ((row & 7) << 3))];
      }
      #pragma unroll
      for (int nj = 0; nj < 4; nj++) {
        int row = wc * 64 + nj * 16 + lr;
        bfp[nj] = *(const short8*)&Bs[row * 64 + ((ks * 32 + lg * 8) ^ ((row & 7) << 3))];
      }
      #pragma unroll
      for (int mi = 0; mi < 4; mi++)
        #pragma unroll
        for (int nj = 0; nj < 4; nj++)
          acc[mi][nj] = __builtin_amdgcn_mfma_f32_16x16x32_bf16(af[mi], bfp[nj], acc[mi][nj], 0, 0, 0);
    }
  }
  proj_epilogue<VT>(acc, bias, outW, m0, n0, wr, wc, lr, lg);
}

// ---------------- sentence attention body ----------------------------------
// smf: >= 7680 floats.
__device__ __forceinline__ void sent_body(
    float* smf, const float* __restrict__ qs, const float* __restrict__ ks,
    const float* __restrict__ vs, float* __restrict__ attn_s,
    float* __restrict__ ctx_s, int bidLocal, int tid)
{
  float* qsS = smf;            // [32][68]
  float* ksS = smf + 2176;
  float* vsS = smf + 4352;
  float* sS  = smf + 6528;     // [32][36]
  const int bh = bidLocal >> 4, b = bh >> 3, h = bh & 7;
  const int q0 = (bidLocal & 15) * 32;

  #pragma unroll
  for (int i = 0; i < 2; i++) {
    int idx = tid + i * 256;
    int r = idx >> 4, c = (idx & 15) * 4;
    *(float4*)&qsS[r * 68 + c] = *(const float4*)&qs[((size_t)bh * 512 + q0 + r) * 64 + c];
    *(float4*)&ksS[r * 68 + c] = *(const float4*)&ks[((size_t)bh * 32 + r) * 64 + c];
    *(float4*)&vsS[r * 68 + c] = *(const float4*)&vs[((size_t)bh * 32 + r) * 64 + c];
  }
  __syncthreads();

  #pragma unroll
  for (int it = 0; it < 4; it++) {
    int pair = tid + it * 256;
    int qq = pair >> 5, nn = pair & 31;
    float s = 0.f;
    #pragma unroll
    for (int k = 0; k < 64; k++) s += qsS[qq * 68 + k] * ksS[nn * 68 + k];
    sS[qq * 36 + nn] = s;
  }
  __syncthreads();

  if (tid < 32) {
    int qq = tid;
    float m = -1e30f;
    #pragma unroll
    for (int n = 0; n < 32; n++) m = fmaxf(m, sS[qq * 36 + n]);
    float p[32];
    float sum = 0.f;
    #pragma unroll
    for (int n = 0; n < 32; n++) { p[n] = __expf(sS[qq * 36 + n] - m); sum += p[n]; }
    float inv = 1.f / sum;
    #pragma unroll
    for (int n = 0; n < 32; n++) {
      float pv = p[n] * inv;
      sS[qq * 36 + n] = pv;
      attn_s[((size_t)bh * 512 + q0 + qq) * 32 + n] = pv;
    }
  }
  __syncthreads();

  #pragma unroll
  for (int it = 0; it < 8; it++) {
    int idx = tid + it * 256;
    int qq = idx >> 6, d = idx & 63;
    float c = 0.f;
    #pragma unroll
    for (int n = 0; n < 32; n++) c += sS[qq * 36 + n] * vsS[n * 68 + d];
    ctx_s[((size_t)b * 512 + q0 + qq) * 512 + h * 64 + d] = c;
  }
}

// ---------------- token attention body (v4.1: halved pbuf, 48KB LDS) --------
// sm: 24576 ushorts = kvbuf[16384] + pbuf[8192].
// Same proven v4 structure/barriers; P stored one t-half at a time
// ([64][128], wave-private rows), PV split into two ks-half phases.
// 48KB -> 3 blocks/CU: the whole 768-block megaB grid is co-resident.
__device__ __forceinline__ void tok_body(
    unsigned short* sm, const float* __restrict__ qw,
    const __hip_bfloat16* __restrict__ kw, const __hip_bfloat16* __restrict__ vwT,
    const float* __restrict__ attn_s, float* __restrict__ part0,
    float* __restrict__ part1, int bid, int tid)
{
  unsigned short* kvbuf = sm;          // K [256][64] XOR  OR  Vt [64][256] XOR
  unsigned short* pbuf  = sm + 16384;  // P [64][128] XOR (one t-half)
  const int xcd = bid & 7, slot = bid >> 3;
  const int bh = xcd * 4 + (slot >> 4);
  const int rest = slot & 15;
  const int qt = rest >> 1, z = rest & 1;
  const int b = bh >> 3, h = bh & 7;
  const int wv = tid >> 6, lane = tid & 63, lg = lane >> 4, lr = lane & 15;
  const int qbase = qt * 64 + wv * 16;
  const int n0 = z * 16;
  const int vd = wv * 16 + (lane >> 2), tq = lane & 3;
  const int swz = (lr & 7) << 3;         // read-side XOR (ushort units)
  const int vswz = (vd & 7) << 3;        // V write-side XOR

  short8 qfrag[2];
  {
    const float* qrow = qw + ((size_t)bh * 512 + qbase + lr) * 64;
    #pragma unroll
    for (int ks = 0; ks < 2; ks++) {
      float4 u0 = *(const float4*)&qrow[ks * 32 + lg * 8];
      float4 u1 = *(const float4*)&qrow[ks * 32 + lg * 8 + 4];
      short8 t;
      t[0] = f2b(u0.x); t[1] = f2b(u0.y); t[2] = f2b(u0.z); t[3] = f2b(u0.w);
      t[4] = f2b(u1.x); t[5] = f2b(u1.y); t[6] = f2b(u1.z); t[7] = f2b(u1.w);
      qfrag[ks] = t;
    }
  }
  float asv[16];
  {
    const float* ap = attn_s + ((size_t)bh * 512 + qbase + lr) * 32 + n0;
    #pragma unroll
    for (int i = 0; i < 4; i++) {
      float4 u = *(const float4*)&ap[i * 4];
      asv[i * 4 + 0] = u.x; asv[i * 4 + 1] = u.y;
      asv[i * 4 + 2] = u.z; asv[i * 4 + 3] = u.w;
    }
  }

  f32x4 acc[4];
  #pragma unroll
  for (int dt = 0; dt < 4; dt++) acc[dt] = (f32x4){0.f, 0.f, 0.f, 0.f};

  const unsigned short* kwb = (const unsigned short*)kw + (size_t)bh * 32 * 256 * 64;
  const unsigned short* vtb = (const unsigned short*)vwT + (size_t)bh * 32 * 64 * 256;
  const unsigned int prow = (wv * 16 + lr) * 128;

  for (int ni = 0; ni < 16; ni++) {
    const int n = n0 + ni;
    __syncthreads();
    {  // stage K: [256][64], XOR chunk swizzle
      const unsigned short* ksrc = kwb + ((size_t)n * 256 + tid) * 64;
      uint4 r[8];
      #pragma unroll
      for (int j = 0; j < 8; j++) r[j] = *(const uint4*)(ksrc + j * 8);
      #pragma unroll
      for (int j = 0; j < 8; j++)
        *(uint4*)&kvbuf[tid * 64 + (((j << 3)) ^ ((tid & 7) << 3))] = r[j];
    }
    __syncthreads();

    f32x4 sfr[16];
    #pragma unroll
    for (int tt = 0; tt < 16; tt++) sfr[tt] = (f32x4){0.f, 0.f, 0.f, 0.f};
    __builtin_amdgcn_s_setprio(1);
    #pragma unroll
    for (int tt = 0; tt < 16; tt++) {
      #pragma unroll
      for (int ks = 0; ks < 2; ks++) {
        short8 kf = *(const short8*)&kvbuf[(16 * tt + lr) * 64 + ((ks * 32 + lg * 8) ^ swz)];
        sfr[tt] = __builtin_amdgcn_mfma_f32_16x16x32_bf16(kf, qfrag[ks], sfr[tt], 0, 0, 0);
      }
    }
    __builtin_amdgcn_s_setprio(0);
    float lsum = 0.f;
    #pragma unroll
    for (int tt = 0; tt < 16; tt++) {
      #pragma unroll
      for (int i = 0; i < 4; i++) {
        float e = __expf(sfr[tt][i]);
        sfr[tt][i] = e;
        lsum += e;
      }
    }
    lsum += __shfl_xor(lsum, 16);
    lsum += __shfl_xor(lsum, 32);
    const float coef = asv[ni] / lsum;
    // P half 0 (tt 0..7 -> t_local 0..127), wave-private rows, stride 128
    #pragma unroll
    for (int tt = 0; tt < 8; tt++) {
      uint2 pk;
      pk.x = (unsigned)f2b(sfr[tt][0] * coef) | ((unsigned)f2b(sfr[tt][1] * coef) << 16);
      pk.y = (unsigned)f2b(sfr[tt][2] * coef) | ((unsigned)f2b(sfr[tt][3] * coef) << 16);
      *(uint2*)&pbuf[prow + ((((tt * 2 + (lg >> 1)) << 3) ^ swz) | ((lg & 1) << 2))] = pk;
    }
    __syncthreads();   // all QK reads of kvbuf done (and orders P-h0 writes)

    {  // stage V: Vt [64][256], XOR chunk swizzle
      const unsigned short* vsrc = vtb + ((size_t)n * 64 + vd) * 256 + tq * 64;
      uint4 r[8];
      #pragma unroll
      for (int j = 0; j < 8; j++) r[j] = *(const uint4*)(vsrc + j * 8);
      #pragma unroll
      for (int j = 0; j < 8; j++)
        *(uint4*)&kvbuf[vd * 256 + ((((tq * 8 + j) << 3)) ^ vswz)] = r[j];
    }
    __syncthreads();

    // PV half 0: t 0..127 (P-h0 + V ks 0..3)
    __builtin_amdgcn_s_setprio(1);
    #pragma unroll
    for (int ks = 0; ks < 4; ks++) {
      short8 pa = *(const short8*)&pbuf[prow + ((ks * 32 + lg * 8) ^ swz)];
      #pragma unroll
      for (int dt = 0; dt < 4; dt++) {
        short8 vb = *(const short8*)&kvbuf[(16 * dt + lr) * 256 + ((ks * 32 + lg * 8) ^ swz)];
        acc[dt] = __builtin_amdgcn_mfma_f32_16x16x32_bf16(pa, vb, acc[dt], 0, 0, 0);
      }
    }
    __builtin_amdgcn_s_setprio(0);
    // P half 1 (tt 8..15 -> t_local 0..127 of second half), same wave-private
    // rows; WAR vs PV-h0 reads is same-wave in-order DS.
    #pragma unroll
    for (int tt = 8; tt < 16; tt++) {
      uint2 pk;
      pk.x = (unsigned)f2b(sfr[tt][0] * coef) | ((unsigned)f2b(sfr[tt][1] * coef) << 16);
      pk.y = (unsigned)f2b(sfr[tt][2] * coef) | ((unsigned)f2b(sfr[tt][3] * coef) << 16);
      *(uint2*)&pbuf[prow + (((((tt - 8) * 2 + (lg >> 1)) << 3) ^ swz) | ((lg & 1) << 2))] = pk;
    }
    asm volatile("s_waitcnt lgkmcnt(0)" ::: "memory");
    __builtin_amdgcn_sched_barrier(0);
    // PV half 1: t 128..255 (P-h1 + V ks 4..7)
    __builtin_amdgcn_s_setprio(1);
    #pragma unroll
    for (int ks = 4; ks < 8; ks++) {
      short8 pa = *(const short8*)&pbuf[prow + (((ks - 4) * 32 + lg * 8) ^ swz)];
      #pragma unroll
      for (int dt = 0; dt < 4; dt++) {
        short8 vb = *(const short8*)&kvbuf[(16 * dt + lr) * 256 + ((ks * 32 + lg * 8) ^ swz)];
        acc[dt] = __builtin_amdgcn_mfma_f32_16x16x32_bf16(pa, vb, acc[dt], 0, 0, 0);
      }
    }
    __builtin_amdgcn_s_setprio(0);
  }

  float* pout = z ? part1 : part0;
  #pragma unroll
  for (int dt = 0; dt < 4; dt++) {
    #pragma unroll
    for (int i = 0; i < 4; i++) {
      int qg = qt * 64 + wv * 16 + lg * 4 + i;
      pout[((size_t)b * 512 + qg) * 512 + h * 64 + dt * 16 + lr] = acc[dt][i];
    }
  }
}

// ---------------- K1: sgemms + wcast + A-casts (all independent) -----------
// [0,512): qs/qw sgemm<2>; [512,544): ks/vs sgemm<3>; [544,672): wcast;
// [672, 672+2*ncast): k_w/v_w f32->bf16 casts.
__global__ __launch_bounds__(256)
void megaQ(const float* __restrict__ q,
           const float* __restrict__ k_s, const float* __restrict__ v_s,
           const float* __restrict__ W_qs, const float* __restrict__ b_qs,
           const float* __restrict__ W_qw, const float* __restrict__ b_qw,
           const float* __restrict__ W_ks, const float* __restrict__ b_ks,
           const float* __restrict__ W_vs, const float* __restrict__ b_vs,
           const float* __restrict__ kwf, const float* __restrict__ vwf,
           unsigned short* __restrict__ kbf, unsigned short* __restrict__ vbf,
           const float* __restrict__ W_kw, unsigned short* __restrict__ WkT,
           const float* __restrict__ W_vw, unsigned short* __restrict__ WvT,
           float* qs_ws, float* qw_ws, float* ks_ws, float* vs_ws, int ncast)
{
  __shared__ __attribute__((aligned(16))) unsigned short sm[16384];
  const int bid = blockIdx.x, tid = threadIdx.x;
  if (bid < 512) {
    int bx = bid & 31, by = (bid >> 5) & 7, bz = bid >> 8;
    if (bz == 0)
      sgemm_body<2>(sm, q, nullptr, nullptr, W_qs, b_qs, qs_ws, SCALE_F, bx * 64, by * 64, 512, tid);
    else
      sgemm_body<2>(sm, q, nullptr, nullptr, W_qw, b_qw, qw_ws, SCALE_F, bx * 64, by * 64, 512, tid);
  } else if (bid < 544) {
    int local = bid - 512;
    int bx = local & 1, by = (local >> 1) & 7, bz = local >> 4;
    if (bz == 0)
      sgemm_body<3>(sm, k_s, nullptr, nullptr, W_ks, b_ks, ks_ws, 1.f, bx * 64, by * 64, 512, tid);
    else
      sgemm_body<3>(sm, v_s, nullptr, nullptr, W_vs, b_vs, vs_ws, 1.f, bx * 64, by * 64, 512, tid);
  } else if (bid < 672) {
    int local = bid - 544;                  // 0..127
    const float* W = (local >> 6) ? W_vw : W_kw;
    unsigned short* T = (local >> 6) ? WvT : WkT;
    int k0 = (local & 7) * 64, n0 = ((local >> 3) & 7) * 64;
    unsigned short* tile = sm;              // [64][72]
    #pragma unroll
    for (int j = 0; j < 16; j++) {
      int idx = tid + j * 256;
      int r = idx >> 6, c = idx & 63;
      tile[r * 72 + c] = f2b(W[(size_t)(k0 + r) * 512 + n0 + c]);
    }
    __syncthreads();
    #pragma unroll
    for (int j = 0; j < 16; j++) {
      int idx = tid + j * 256;
      int r = idx >> 6, c = idx & 63;
      T[(size_t)(n0 + r) * 512 + k0 + c] = tile[c * 72 + r];
    }
  } else {
    int local = bid - 672;
    const float* src = (local < ncast) ? kwf : vwf;
    unsigned short* dst = (local < ncast) ? kbf : vbf;
    size_t off = (size_t)((local < ncast) ? local : local - ncast) * 8192;
    #pragma unroll
    for (int i = 0; i < 8; i++) {
      size_t idx = off + ((size_t)i * 256 + tid) * 4;
      float4 v = *(const float4*)&src[idx];
      uint2 pk;
      pk.x = (unsigned)f2b(v.x) | ((unsigned)f2b(v.y) << 16);
      pk.y = (unsigned)f2b(v.z) | ((unsigned)f2b(v.w) << 16);
      *(uint2*)&dst[idx] = pk;
    }
  }
}

// ---------------- K2: big projections + sentence attention -----------------
// [0,1024): proj<0>; [1024,2048): proj<1>; [2048,2560): sent_attn.
__global__ __launch_bounds__(256)
void megaP_glds(const unsigned short* __restrict__ kbf,
                const unsigned short* __restrict__ vbf,
                const unsigned short* __restrict__ WkT, const float* __restrict__ b_kw,
                const unsigned short* __restrict__ WvT, const float* __restrict__ b_vw,
                __hip_bfloat16* kw_ws, __hip_bfloat16* vwT_ws,
                const float* __restrict__ qs, const float* __restrict__ ks,
                const float* __restrict__ vs, float* attn_s, float* ctx_s)
{
  __shared__ __attribute__((aligned(16))) unsigned short sm[16384];
  const int bid = blockIdx.x, tid = threadIdx.x;
  if (bid < 1024) {
    proj_glds<0>(sm, kbf, WkT, b_kw, kw_ws, bid, tid);
  } else if (bid < 2048) {
    proj_glds<1>(sm, vbf, WvT, b_vw, vwT_ws, bid - 1024, tid);
  } else {
    sent_body((float*)sm, qs, ks, vs, attn_s, ctx_s, bid - 2048, tid);
  }
}

__global__ __launch_bounds__(256)
void megaP_reg(const float* __restrict__ k_w, const float* __restrict__ v_w,
               const unsigned short* __restrict__ WkT, const float* __restrict__ b_kw,
               const unsigned short* __restrict__ WvT, const float* __restrict__ b_vw,
               __hip_bfloat16* kw_ws, __hip_bfloat16* vwT_ws,
               const float* __restrict__ qs, const float* __restrict__ ks,
               const float* __restrict__ vs, float* attn_s, float* ctx_s)
{
  __shared__ __attribute__((aligned(16))) unsigned short sm[16384];
  const int bid = blockIdx.x, tid = threadIdx.x;
  if (bid < 1024) {
    proj_reg<0>(sm, k_w, WkT, b_kw, kw_ws, bid, tid);
  } else if (bid < 2048) {
    proj_reg<1>(sm, v_w, WvT, b_vw, vwT_ws, bid - 1024, tid);
  } else {
    sent_body((float*)sm, qs, ks, vs, attn_s, ctx_s, bid - 2048, tid);
  }
}

// ---------------- K3: token attention + fc1 GEMM ---------------------------
// 48KB static LDS -> 3 blocks/CU -> all 768 blocks co-resident.
__global__ __launch_bounds__(256, 3)
void megaB(const float* __restrict__ qw,
           const __hip_bfloat16* __restrict__ kw, const __hip_bfloat16* __restrict__ vwT,
           const float* __restrict__ attn_s, float* part0, float* part1,
           const float* __restrict__ ctxs,
           const float* __restrict__ W_fc1, const float* __restrict__ b_fc1,
           float* ctxsf)
{
  __shared__ __attribute__((aligned(16))) unsigned short sm[24576];
  const int bid = blockIdx.x, tid = threadIdx.x;
  if (bid < 512) {
    tok_body(sm, qw, kw, vwT, attn_s, part0, part1, bid, tid);
  } else {
    int local = bid - 512;
    sgemm_body<0>(sm, ctxs, nullptr, nullptr, W_fc1, b_fc1, ctxsf, 1.f,
                  (local & 31) * 64, (local >> 5) * 64, 512, tid);
  }
}

// ---------------- K4: final combine GEMM -----------------------------------
__global__ __launch_bounds__(256)
void final_gemm(const float* __restrict__ ctxsf,
                const float* __restrict__ p0, const float* __restrict__ p1,
                const float* __restrict__ W, const float* __restrict__ bias,
                float* out)
{
  __shared__ __attribute__((aligned(16))) unsigned short sm[16384];
  sgemm_body<1>(sm, ctxsf, p0, p1, W, bias, out, 1.f,
                blockIdx.x * 64, blockIdx.y * 64, 1024, threadIdx.x);
}

extern "C" void kernel_launch(void* const* d_in, const int* in_sizes, int n_in,
                              void* d_out, int out_size, void* d_ws, size_t ws_size,
                              hipStream_t stream)
{
  (void)in_sizes; (void)n_in; (void)out_size;
  const float* q    = (const float*)d_in[0];
  const float* k_w  = (const float*)d_in[1];
  const float* v_w  = (const float*)d_in[2];
  const float* k_s  = (const float*)d_in[3];
  const float* v_s  = (const float*)d_in[4];
  const float* W_qs = (const float*)d_in[5];  const float* b_qs = (const float*)d_in[6];
  const float* W_ks = (const float*)d_in[7];  const float* b_ks = (const float*)d_in[8];
  const float* W_vs = (const float*)d_in[9];  const float* b_vs = (const float*)d_in[10];
  const float* W_qw = (const float*)d_in[11]; const float* b_qw = (const float*)d_in[12];
  const float* W_kw = (const float*)d_in[13]; const float* b_kw = (const float*)d_in[14];
  const float* W_vw = (const float*)d_in[15]; const float* b_vw = (const float*)d_in[16];
  const float* W_fc1= (const float*)d_in[17]; const float* b_fc1= (const float*)d_in[18];
  const float* W_fc = (const float*)d_in[19]; const float* b_fc = (const float*)d_in[20];
  float* out = (float*)d_out;

  char* ws = (char*)d_ws;
  const size_t MB = 1ull << 20;
  const size_t KB = 1ull << 10;
  float* qs_ws    = (float*)(ws + 0 * MB);       // [b,h,512,64] 4 MB (dead after sent_attn)
  float* qw_ws    = (float*)(ws + 4 * MB);       // [b,h,512,64] 4 MB
  float* ks_ws    = (float*)(ws + 8 * MB);       // [b,h,32,64] 256 KB
  unsigned short* WkT = (unsigned short*)(ws + 8 * MB + 512 * KB);  // 512 KB
  float* vs_ws    = (float*)(ws + 9 * MB);       // [b,h,32,64] 256 KB
  unsigned short* WvT = (unsigned short*)(ws + 9 * MB + 512 * KB);  // 512 KB
  float* attns_ws = (float*)(ws + 10 * MB);      // [b,h,512,32] 2 MB
  float* ctxs_ws  = (float*)(ws + 12 * MB);      // [b,512,512] 4 MB (read by fc1 in megaB)
  float* ctxsf_ws = (float*)(ws + 16 * MB);      // [b,512,512] 4 MB
  float* part1    = (float*)(ws + 20 * MB);      // [b,512,512] 4 MB
  __hip_bfloat16* kw_ws  = (__hip_bfloat16*)(ws + 24 * MB);  // [b,h,32,256,64] 32 MB
  __hip_bfloat16* vwT_ws = (__hip_bfloat16*)(ws + 56 * MB);  // [b,h,32,64,256] 32 MB
  unsigned short* kbf = (unsigned short*)(ws + 88 * MB);     // [32768][512] bf16 32 MB
  unsigned short* vbf = (unsigned short*)(ws + 120 * MB);    // 32 MB
  float* part0    = (float*)(ws + 0 * MB);       // over qs_ws (dead by megaB)

  const bool use_glds = (ws_size >= 152ull * MB);
  const int ncast = use_glds ? 2048 : 0;

  dim3 blk(256);
  // K1: small projections + weight transpose-casts + A bf16 casts (independent)
  megaQ<<<dim3(672 + 2 * ncast), blk, 0, stream>>>(
      q, k_s, v_s, W_qs, b_qs, W_qw, b_qw, W_ks, b_ks, W_vs, b_vs,
      k_w, v_w, kbf, vbf, W_kw, WkT, W_vw, WvT,
      qs_ws, qw_ws, ks_ws, vs_ws, ncast);
  // K2: big projections + sentence attention
  if (use_glds) {
    megaP_glds<<<dim3(2560), blk, 0, stream>>>(
        kbf, vbf, WkT, b_kw, WvT, b_vw, kw_ws, vwT_ws,
        qs_ws, ks_ws, vs_ws, attns_ws, ctxs_ws);
  } else {
    megaP_reg<<<dim3(2560), blk, 0, stream>>>(
        k_w, v_w, WkT, b_kw, WvT, b_vw, kw_ws, vwT_ws,
        qs_ws, ks_ws, vs_ws, attns_ws, ctxs_ws);
  }
  // K3: token attention (512 blocks, 48KB) + fc1 GEMM (256 blocks)
  megaB<<<dim3(768), blk, 0, stream>>>(
      qw_ws, kw_ws, vwT_ws, attns_ws, part0, part1,
      ctxs_ws, W_fc1, b_fc1, ctxsf_ws);
  // K4: final combine: concat([ctx_s_fc1, part0+part1]) @ W_fc + b_fc
  final_gemm<<<dim3(32, 8), blk, 0, stream>>>(ctxsf_ws, part0, part1, W_fc, b_fc, out);
}

// Round 18
// 238.572 us; speedup vs baseline: 1.0358x; 1.0358x over previous
//
#include <hip/hip_runtime.h>
#include <hip/hip_bf16.h>

#define SCALE_F 0.125f

typedef __attribute__((ext_vector_type(8))) short short8;
typedef __attribute__((ext_vector_type(4))) float f32x4;
typedef __attribute__((address_space(3))) void lds_void;
typedef const __attribute__((address_space(1))) void glb_void;

__device__ __forceinline__ unsigned short f2b(float f){
  return __builtin_bit_cast(unsigned short, __float2bfloat16(f));
}
__device__ __forceinline__ float b2f(unsigned short h){
  return __uint_as_float((unsigned int)h << 16);
}

// ---------------- sgemm body (bf16x3 split, 64x64 tile, BK=64) -------------
// sm: 16384 ushorts.  MODE 0/2/3: plain/Q-layout/S-layout f32 out.
// MODE 1: K=1024, k>=512 A-rows come from p0+p1.
template<int MODE>
__device__ __forceinline__ void sgemm_body(
    unsigned short* sm, const float* __restrict__ A,
    const float* __restrict__ p0, const float* __restrict__ p1,
    const float* __restrict__ W, const float* __restrict__ bias,
    float* __restrict__ outf, float scale, int m0, int n0, int K, int tid)
{
  unsigned short* Ah = sm;
  unsigned short* Al = sm + 4096;
  unsigned short* Bh = sm + 8192;
  unsigned short* Bl = sm + 12288;
  const int lane = tid & 63, wv = tid >> 6, lr = lane & 15, lg = lane >> 4;

  f32x4 acc[4];
  #pragma unroll
  for (int nf = 0; nf < 4; nf++) acc[nf] = (f32x4){0.f, 0.f, 0.f, 0.f};

  for (int k0 = 0; k0 < K; k0 += 64) {
    float4 a0[2], a1[2];
    float bw[2][8];
    const bool dual = (MODE == 1) && (k0 >= 512);
    const int kk = dual ? (k0 - 512) : k0;
    #pragma unroll
    for (int j = 0; j < 2; j++) {
      int idx = tid + j * 256;
      int row = idx >> 3, c8 = idx & 7;
      size_t base = (size_t)(m0 + row) * 512 + kk + c8 * 8;
      if (dual) {
        float4 x0 = *(const float4*)&p0[base];
        float4 x1 = *(const float4*)&p0[base + 4];
        float4 y0 = *(const float4*)&p1[base];
        float4 y1 = *(const float4*)&p1[base + 4];
        a0[j] = (float4){x0.x + y0.x, x0.y + y0.y, x0.z + y0.z, x0.w + y0.w};
        a1[j] = (float4){x1.x + y1.x, x1.y + y1.y, x1.z + y1.z, x1.w + y1.w};
      } else {
        a0[j] = *(const float4*)&A[base];
        a1[j] = *(const float4*)&A[base + 4];
      }
    }
    #pragma unroll
    for (int j = 0; j < 2; j++) {
      int idx = tid + j * 256;
      int nl = idx >> 3, kseg = idx & 7;
      #pragma unroll
      for (int e = 0; e < 8; e++)
        bw[j][e] = W[(size_t)(k0 + kseg * 8 + e) * 512 + n0 + nl];
    }
    __syncthreads();
    #pragma unroll
    for (int j = 0; j < 2; j++) {
      int idx = tid + j * 256;
      int row = idx >> 3, c8 = idx & 7;
      int off = row * 64 + ((c8 * 8) ^ ((row & 7) << 3));
      float v[8] = {a0[j].x, a0[j].y, a0[j].z, a0[j].w,
                    a1[j].x, a1[j].y, a1[j].z, a1[j].w};
      short8 h, l;
      #pragma unroll
      for (int e = 0; e < 8; e++) {
        unsigned short hh = f2b(v[e]);
        h[e] = (short)hh;
        l[e] = (short)f2b(v[e] - b2f(hh));
      }
      *(short8*)&Ah[off] = h;
      *(short8*)&Al[off] = l;
    }
    #pragma unroll
    for (int j = 0; j < 2; j++) {
      int idx = tid + j * 256;
      int nl = idx >> 3, kseg = idx & 7;
      int off = nl * 64 + ((kseg * 8) ^ ((nl & 7) << 3));
      short8 h, l;
      #pragma unroll
      for (int e = 0; e < 8; e++) {
        unsigned short hh = f2b(bw[j][e]);
        h[e] = (short)hh;
        l[e] = (short)f2b(bw[j][e] - b2f(hh));
      }
      *(short8*)&Bh[off] = h;
      *(short8*)&Bl[off] = l;
    }
    __syncthreads();
    #pragma unroll
    for (int ks = 0; ks < 2; ks++) {
      int rowa = wv * 16 + lr;
      int aoff = rowa * 64 + ((ks * 32 + lg * 8) ^ ((rowa & 7) << 3));
      short8 ah = *(const short8*)&Ah[aoff];
      short8 al = *(const short8*)&Al[aoff];
      #pragma unroll
      for (int nf = 0; nf < 4; nf++) {
        int rowb = nf * 16 + lr;
        int boff = rowb * 64 + ((ks * 32 + lg * 8) ^ ((rowb & 7) << 3));
        short8 bh = *(const short8*)&Bh[boff];
        short8 bl = *(const short8*)&Bl[boff];
        acc[nf] = __builtin_amdgcn_mfma_f32_16x16x32_bf16(ah, bh, acc[nf], 0, 0, 0);
        acc[nf] = __builtin_amdgcn_mfma_f32_16x16x32_bf16(ah, bl, acc[nf], 0, 0, 0);
        acc[nf] = __builtin_amdgcn_mfma_f32_16x16x32_bf16(al, bh, acc[nf], 0, 0, 0);
      }
    }
  }

  #pragma unroll
  for (int nf = 0; nf < 4; nf++) {
    int n = n0 + nf * 16 + lr;
    float bv = bias[n];
    #pragma unroll
    for (int i = 0; i < 4; i++) {
      int m = m0 + wv * 16 + lg * 4 + i;
      float v = (acc[nf][i] + bv) * scale;
      if (MODE == 0 || MODE == 1) {
        outf[(size_t)m * 512 + n] = v;
      } else if (MODE == 2) {
        int bb = m >> 9, qq = m & 511, hh = n >> 6, d = n & 63;
        outf[((((size_t)bb * 8 + hh) * 512 + qq) << 6) + d] = v;
      } else {
        int bb = m >> 5, nn = m & 31, hh = n >> 6, d = n & 63;
        outf[((((size_t)bb * 8 + hh) * 32 + nn) << 6) + d] = v;
      }
    }
  }
}

// -------- proj epilogue (shared by both staging variants) -------------------
template<int VT>
__device__ __forceinline__ void proj_epilogue(
    f32x4 (&acc)[4][4], const float* __restrict__ bias,
    __hip_bfloat16* __restrict__ outW, int m0, int n0,
    int wr, int wc, int lr, int lg)
{
  #pragma unroll
  for (int nj = 0; nj < 4; nj++) {
    int n = n0 + wc * 64 + nj * 16 + lr;
    float bv = bias[n];
    int hh = n >> 6, d = n & 63;
    #pragma unroll
    for (int mi = 0; mi < 4; mi++) {
      if (VT == 0) {
        #pragma unroll
        for (int i = 0; i < 4; i++) {
          int m = m0 + wr * 64 + mi * 16 + lg * 4 + i;
          int bb = m >> 13, r = m & 8191, nn = r >> 8, tt = r & 255;
          outW[(((((size_t)bb * 8 + hh) * 32 + nn) * 256 + tt) << 6) + d] =
              __float2bfloat16(acc[mi][nj][i] + bv);
        }
      } else {
        int m = m0 + wr * 64 + mi * 16 + lg * 4;   // 4 consecutive t
        int bb = m >> 13, r = m & 8191, nn = r >> 8, t0 = r & 255;
        uint2 pk;
        pk.x = (unsigned)f2b(acc[mi][nj][0] + bv) | ((unsigned)f2b(acc[mi][nj][1] + bv) << 16);
        pk.y = (unsigned)f2b(acc[mi][nj][2] + bv) | ((unsigned)f2b(acc[mi][nj][3] + bv) << 16);
        *(uint2*)((unsigned short*)outW +
                  (((((size_t)bb * 8 + hh) * 32 + nn) * 64 + d) << 8) + t0) = pk;
      }
    }
  }
}

// ------------- proj body, reg-staged variant (fallback) --------------------
template<int VT>
__device__ __forceinline__ void proj_reg(
    unsigned short* sm, const float* __restrict__ A,
    const unsigned short* __restrict__ BT, const float* __restrict__ bias,
    __hip_bfloat16* __restrict__ outW, int bidLocal, int tid)
{
  unsigned short* As = sm;
  unsigned short* Bs = sm + 8192;
  const int xcd = bidLocal & 7, local = bidLocal >> 3;
  const int mx = xcd * 32 + (local >> 2);
  const int ny = local & 3;
  const int m0 = mx * 128, n0 = ny * 128;
  const int lane = tid & 63, wv = tid >> 6, lr = lane & 15, lg = lane >> 4;
  const int wr = wv >> 1, wc = wv & 1;

  f32x4 acc[4][4];
  #pragma unroll
  for (int mi = 0; mi < 4; mi++)
    #pragma unroll
    for (int nj = 0; nj < 4; nj++) acc[mi][nj] = (f32x4){0.f, 0.f, 0.f, 0.f};

  for (int k0 = 0; k0 < 512; k0 += 64) {
    float4 a0[4], a1[4]; uint4 bq[4];
    #pragma unroll
    for (int j = 0; j < 4; j++) {
      int idx = tid + j * 256;
      int row = idx >> 3, c8 = idx & 7;
      const float* ap = A + (size_t)(m0 + row) * 512 + k0 + c8 * 8;
      a0[j] = *(const float4*)ap;
      a1[j] = *(const float4*)(ap + 4);
      bq[j] = *(const uint4*)(BT + (size_t)(n0 + row) * 512 + k0 + c8 * 8);
    }
    __syncthreads();
    #pragma unroll
    for (int j = 0; j < 4; j++) {
      int idx = tid + j * 256;
      int row = idx >> 3, c8 = idx & 7;
      int off = row * 64 + ((c8 * 8) ^ ((row & 7) << 3));
      short8 pk;
      pk[0] = (short)f2b(a0[j].x); pk[1] = (short)f2b(a0[j].y);
      pk[2] = (short)f2b(a0[j].z); pk[3] = (short)f2b(a0[j].w);
      pk[4] = (short)f2b(a1[j].x); pk[5] = (short)f2b(a1[j].y);
      pk[6] = (short)f2b(a1[j].z); pk[7] = (short)f2b(a1[j].w);
      *(short8*)&As[off] = pk;
      *(uint4*)&Bs[off] = bq[j];
    }
    __syncthreads();
    #pragma unroll
    for (int ks = 0; ks < 2; ks++) {
      short8 af[4], bfp[4];
      #pragma unroll
      for (int mi = 0; mi < 4; mi++) {
        int row = wr * 64 + mi * 16 + lr;
        af[mi] = *(const short8*)&As[row * 64 + ((ks * 32 + lg * 8) ^ ((row & 7) << 3))];
      }
      #pragma unroll
      for (int nj = 0; nj < 4; nj++) {
        int row = wc * 64 + nj * 16 + lr;
        bfp[nj] = *(const short8*)&Bs[row * 64 + ((ks * 32 + lg * 8) ^ ((row & 7) << 3))];
      }
      #pragma unroll
      for (int mi = 0; mi < 4; mi++)
        #pragma unroll
        for (int nj = 0; nj < 4; nj++)
          acc[mi][nj] = __builtin_amdgcn_mfma_f32_16x16x32_bf16(af[mi], bfp[nj], acc[mi][nj], 0, 0, 0);
    }
  }
  proj_epilogue<VT>(acc, bias, outW, m0, n0, wr, wc, lr, lg);
}

// ------------- proj body, global_load_lds variant ---------------------------
template<int VT>
__device__ __forceinline__ void proj_glds(
    unsigned short* sm, const unsigned short* __restrict__ Abf,
    const unsigned short* __restrict__ BT, const float* __restrict__ bias,
    __hip_bfloat16* __restrict__ outW, int bidLocal, int tid)
{
  unsigned short* As = sm;
  unsigned short* Bs = sm + 8192;
  const int xcd = bidLocal & 7, local = bidLocal >> 3;
  const int mx = xcd * 32 + (local >> 2);
  const int ny = local & 3;
  const int m0 = mx * 128, n0 = ny * 128;
  const int lane = tid & 63, wv = tid >> 6, lr = lane & 15, lg = lane >> 4;
  const int wr = wv >> 1, wc = wv & 1;
  const int srow = tid >> 3, scc = tid & 7;

  f32x4 acc[4][4];
  #pragma unroll
  for (int mi = 0; mi < 4; mi++)
    #pragma unroll
    for (int nj = 0; nj < 4; nj++) acc[mi][nj] = (f32x4){0.f, 0.f, 0.f, 0.f};

  for (int k0 = 0; k0 < 512; k0 += 64) {
    __syncthreads();
    #pragma unroll
    for (int issue = 0; issue < 4; issue++) {
      int row = issue * 32 + srow;
      int cs = (scc ^ (row & 7)) * 8;
      const unsigned short* ga = Abf + (size_t)(m0 + row) * 512 + k0 + cs;
      const unsigned short* gb = BT  + (size_t)(n0 + row) * 512 + k0 + cs;
      unsigned short* la = As + issue * 2048 + wv * 512;
      unsigned short* lb = Bs + issue * 2048 + wv * 512;
      __builtin_amdgcn_global_load_lds((glb_void*)ga, (lds_void*)la, 16, 0, 0);
      __builtin_amdgcn_global_load_lds((glb_void*)gb, (lds_void*)lb, 16, 0, 0);
    }
    asm volatile("s_waitcnt vmcnt(0)" ::: "memory");
    __syncthreads();
    #pragma unroll
    for (int ks = 0; ks < 2; ks++) {
      short8 af[4], bfp[4];
      #pragma unroll
      for (int mi = 0; mi < 4; mi++) {
        int row = wr * 64 + mi * 16 + lr;
        af[mi] = *(const short8*)&As[row * 64 + ((ks * 32 + lg * 8) ^ ((row & 7) << 3))];
      }
      #pragma unroll
      for (int nj = 0; nj < 4; nj++) {
        int row = wc * 64 + nj * 16 + lr;
        bfp[nj] = *(const short8*)&Bs[row * 64 + ((ks * 32 + lg * 8) ^ ((row & 7) << 3))];
      }
      #pragma unroll
      for (int mi = 0; mi < 4; mi++)
        #pragma unroll
        for (int nj = 0; nj < 4; nj++)
          acc[mi][nj] = __builtin_amdgcn_mfma_f32_16x16x32_bf16(af[mi], bfp[nj], acc[mi][nj], 0, 0, 0);
    }
  }
  proj_epilogue<VT>(acc, bias, outW, m0, n0, wr, wc, lr, lg);
}

// ---------------- sentence attention body ----------------------------------
// smf: >= 7680 floats.
__device__ __forceinline__ void sent_body(
    float* smf, const float* __restrict__ qs, const float* __restrict__ ks,
    const float* __restrict__ vs, float* __restrict__ attn_s,
    float* __restrict__ ctx_s, int bidLocal, int tid)
{
  float* qsS = smf;            // [32][68]
  float* ksS = smf + 2176;
  float* vsS = smf + 4352;
  float* sS  = smf + 6528;     // [32][36]
  const int bh = bidLocal >> 4, b = bh >> 3, h = bh & 7;
  const int q0 = (bidLocal & 15) * 32;

  #pragma unroll
  for (int i = 0; i < 2; i++) {
    int idx = tid + i * 256;
    int r = idx >> 4, c = (idx & 15) * 4;
    *(float4*)&qsS[r * 68 + c] = *(const float4*)&qs[((size_t)bh * 512 + q0 + r) * 64 + c];
    *(float4*)&ksS[r * 68 + c] = *(const float4*)&ks[((size_t)bh * 32 + r) * 64 + c];
    *(float4*)&vsS[r * 68 + c] = *(const float4*)&vs[((size_t)bh * 32 + r) * 64 + c];
  }
  __syncthreads();

  #pragma unroll
  for (int it = 0; it < 4; it++) {
    int pair = tid + it * 256;
    int qq = pair >> 5, nn = pair & 31;
    float s = 0.f;
    #pragma unroll
    for (int k = 0; k < 64; k++) s += qsS[qq * 68 + k] * ksS[nn * 68 + k];
    sS[qq * 36 + nn] = s;
  }
  __syncthreads();

  if (tid < 32) {
    int qq = tid;
    float m = -1e30f;
    #pragma unroll
    for (int n = 0; n < 32; n++) m = fmaxf(m, sS[qq * 36 + n]);
    float p[32];
    float sum = 0.f;
    #pragma unroll
    for (int n = 0; n < 32; n++) { p[n] = __expf(sS[qq * 36 + n] - m); sum += p[n]; }
    float inv = 1.f / sum;
    #pragma unroll
    for (int n = 0; n < 32; n++) {
      float pv = p[n] * inv;
      sS[qq * 36 + n] = pv;
      attn_s[((size_t)bh * 512 + q0 + qq) * 32 + n] = pv;
    }
  }
  __syncthreads();

  #pragma unroll
  for (int it = 0; it < 8; it++) {
    int idx = tid + it * 256;
    int qq = idx >> 6, d = idx & 63;
    float c = 0.f;
    #pragma unroll
    for (int n = 0; n < 32; n++) c += sS[qq * 36 + n] * vsS[n * 68 + d];
    ctx_s[((size_t)b * 512 + q0 + qq) * 512 + h * 64 + d] = c;
  }
}

// ---------------- token attention body (v4, PROVEN round-13/16) -------------
// sm: 32768 ushorts = kvbuf[16384] + pbuf[16384].
__device__ __forceinline__ void tok_body(
    unsigned short* sm, const float* __restrict__ qw,
    const __hip_bfloat16* __restrict__ kw, const __hip_bfloat16* __restrict__ vwT,
    const float* __restrict__ attn_s, float* __restrict__ part0,
    float* __restrict__ part1, int bid, int tid)
{
  unsigned short* kvbuf = sm;          // K [256][64] XOR  OR  Vt [64][256] XOR
  unsigned short* pbuf  = sm + 16384;  // P [64][256] XOR
  const int xcd = bid & 7, slot = bid >> 3;
  const int bh = xcd * 4 + (slot >> 4);
  const int rest = slot & 15;
  const int qt = rest >> 1, z = rest & 1;
  const int b = bh >> 3, h = bh & 7;
  const int wv = tid >> 6, lane = tid & 63, lg = lane >> 4, lr = lane & 15;
  const int qbase = qt * 64 + wv * 16;
  const int n0 = z * 16;
  const int vd = wv * 16 + (lane >> 2), tq = lane & 3;
  const int swz = (lr & 7) << 3;         // read-side XOR (ushort units)
  const int vswz = (vd & 7) << 3;        // V write-side XOR

  short8 qfrag[2];
  {
    const float* qrow = qw + ((size_t)bh * 512 + qbase + lr) * 64;
    #pragma unroll
    for (int ks = 0; ks < 2; ks++) {
      float4 u0 = *(const float4*)&qrow[ks * 32 + lg * 8];
      float4 u1 = *(const float4*)&qrow[ks * 32 + lg * 8 + 4];
      short8 t;
      t[0] = f2b(u0.x); t[1] = f2b(u0.y); t[2] = f2b(u0.z); t[3] = f2b(u0.w);
      t[4] = f2b(u1.x); t[5] = f2b(u1.y); t[6] = f2b(u1.z); t[7] = f2b(u1.w);
      qfrag[ks] = t;
    }
  }
  float asv[16];
  {
    const float* ap = attn_s + ((size_t)bh * 512 + qbase + lr) * 32 + n0;
    #pragma unroll
    for (int i = 0; i < 4; i++) {
      float4 u = *(const float4*)&ap[i * 4];
      asv[i * 4 + 0] = u.x; asv[i * 4 + 1] = u.y;
      asv[i * 4 + 2] = u.z; asv[i * 4 + 3] = u.w;
    }
  }

  f32x4 acc[4];
  #pragma unroll
  for (int dt = 0; dt < 4; dt++) acc[dt] = (f32x4){0.f, 0.f, 0.f, 0.f};

  const unsigned short* kwb = (const unsigned short*)kw + (size_t)bh * 32 * 256 * 64;
  const unsigned short* vtb = (const unsigned short*)vwT + (size_t)bh * 32 * 64 * 256;
  const unsigned int prow = (wv * 16 + lr) * 256;

  for (int ni = 0; ni < 16; ni++) {
    const int n = n0 + ni;
    __syncthreads();
    {  // stage K: [256][64], XOR chunk swizzle
      const unsigned short* ksrc = kwb + ((size_t)n * 256 + tid) * 64;
      uint4 r[8];
      #pragma unroll
      for (int j = 0; j < 8; j++) r[j] = *(const uint4*)(ksrc + j * 8);
      #pragma unroll
      for (int j = 0; j < 8; j++)
        *(uint4*)&kvbuf[tid * 64 + (((j << 3)) ^ ((tid & 7) << 3))] = r[j];
    }
    __syncthreads();

    f32x4 sfr[16];
    #pragma unroll
    for (int tt = 0; tt < 16; tt++) sfr[tt] = (f32x4){0.f, 0.f, 0.f, 0.f};
    __builtin_amdgcn_s_setprio(1);
    #pragma unroll
    for (int tt = 0; tt < 16; tt++) {
      #pragma unroll
      for (int ks = 0; ks < 2; ks++) {
        short8 kf = *(const short8*)&kvbuf[(16 * tt + lr) * 64 + ((ks * 32 + lg * 8) ^ swz)];
        sfr[tt] = __builtin_amdgcn_mfma_f32_16x16x32_bf16(kf, qfrag[ks], sfr[tt], 0, 0, 0);
      }
    }
    __builtin_amdgcn_s_setprio(0);
    float lsum = 0.f;
    #pragma unroll
    for (int tt = 0; tt < 16; tt++) {
      #pragma unroll
      for (int i = 0; i < 4; i++) {
        float e = __expf(sfr[tt][i]);
        sfr[tt][i] = e;
        lsum += e;
      }
    }
    lsum += __shfl_xor(lsum, 16);
    lsum += __shfl_xor(lsum, 32);
    const float coef = asv[ni] / lsum;
    #pragma unroll
    for (int tt = 0; tt < 16; tt++) {
      uint2 pk;
      pk.x = (unsigned)f2b(sfr[tt][0] * coef) | ((unsigned)f2b(sfr[tt][1] * coef) << 16);
      pk.y = (unsigned)f2b(sfr[tt][2] * coef) | ((unsigned)f2b(sfr[tt][3] * coef) << 16);
      // col = tt*16 + lg*4 -> chunk = tt*2 + (lg>>1), sub = (lg&1)*4
      *(uint2*)&pbuf[prow + ((((tt * 2 + (lg >> 1)) << 3) ^ swz) | ((lg & 1) << 2))] = pk;
    }
    __syncthreads();

    {  // stage V: Vt [64][256], XOR chunk swizzle
      const unsigned short* vsrc = vtb + ((size_t)n * 64 + vd) * 256 + tq * 64;
      uint4 r[8];
      #pragma unroll
      for (int j = 0; j < 8; j++) r[j] = *(const uint4*)(vsrc + j * 8);
      #pragma unroll
      for (int j = 0; j < 8; j++)
        *(uint4*)&kvbuf[vd * 256 + ((((tq * 8 + j) << 3)) ^ vswz)] = r[j];
    }
    __syncthreads();

    __builtin_amdgcn_s_setprio(1);
    #pragma unroll
    for (int ks = 0; ks < 8; ks++) {
      short8 pa = *(const short8*)&pbuf[prow + ((ks * 32 + lg * 8) ^ swz)];
      #pragma unroll
      for (int dt = 0; dt < 4; dt++) {
        short8 vb = *(const short8*)&kvbuf[(16 * dt + lr) * 256 + ((ks * 32 + lg * 8) ^ swz)];
        acc[dt] = __builtin_amdgcn_mfma_f32_16x16x32_bf16(pa, vb, acc[dt], 0, 0, 0);
      }
    }
    __builtin_amdgcn_s_setprio(0);
  }

  float* pout = z ? part1 : part0;
  #pragma unroll
  for (int dt = 0; dt < 4; dt++) {
    #pragma unroll
    for (int i = 0; i < 4; i++) {
      int qg = qt * 64 + wv * 16 + lg * 4 + i;
      pout[((size_t)b * 512 + qg) * 512 + h * 64 + dt * 16 + lr] = acc[dt][i];
    }
  }
}

// ---------------- K1: sgemms + wcast + A-casts (all independent) -----------
// [0,512): qs/qw sgemm<2>; [512,544): ks/vs sgemm<3>; [544,672): wcast;
// [672, 672+2*ncast): k_w/v_w f32->bf16 casts.
__global__ __launch_bounds__(256)
void megaQ(const float* __restrict__ q,
           const float* __restrict__ k_s, const float* __restrict__ v_s,
           const float* __restrict__ W_qs, const float* __restrict__ b_qs,
           const float* __restrict__ W_qw, const float* __restrict__ b_qw,
           const float* __restrict__ W_ks, const float* __restrict__ b_ks,
           const float* __restrict__ W_vs, const float* __restrict__ b_vs,
           const float* __restrict__ kwf, const float* __restrict__ vwf,
           unsigned short* __restrict__ kbf, unsigned short* __restrict__ vbf,
           const float* __restrict__ W_kw, unsigned short* __restrict__ WkT,
           const float* __restrict__ W_vw, unsigned short* __restrict__ WvT,
           float* qs_ws, float* qw_ws, float* ks_ws, float* vs_ws, int ncast)
{
  __shared__ __attribute__((aligned(16))) unsigned short sm[16384];
  const int bid = blockIdx.x, tid = threadIdx.x;
  if (bid < 512) {
    int bx = bid & 31, by = (bid >> 5) & 7, bz = bid >> 8;
    if (bz == 0)
      sgemm_body<2>(sm, q, nullptr, nullptr, W_qs, b_qs, qs_ws, SCALE_F, bx * 64, by * 64, 512, tid);
    else
      sgemm_body<2>(sm, q, nullptr, nullptr, W_qw, b_qw, qw_ws, SCALE_F, bx * 64, by * 64, 512, tid);
  } else if (bid < 544) {
    int local = bid - 512;
    int bx = local & 1, by = (local >> 1) & 7, bz = local >> 4;
    if (bz == 0)
      sgemm_body<3>(sm, k_s, nullptr, nullptr, W_ks, b_ks, ks_ws, 1.f, bx * 64, by * 64, 512, tid);
    else
      sgemm_body<3>(sm, v_s, nullptr, nullptr, W_vs, b_vs, vs_ws, 1.f, bx * 64, by * 64, 512, tid);
  } else if (bid < 672) {
    int local = bid - 544;                  // 0..127
    const float* W = (local >> 6) ? W_vw : W_kw;
    unsigned short* T = (local >> 6) ? WvT : WkT;
    int k0 = (local & 7) * 64, n0 = ((local >> 3) & 7) * 64;
    unsigned short* tile = sm;              // [64][72]
    #pragma unroll
    for (int j = 0; j < 16; j++) {
      int idx = tid + j * 256;
      int r = idx >> 6, c = idx & 63;
      tile[r * 72 + c] = f2b(W[(size_t)(k0 + r) * 512 + n0 + c]);
    }
    __syncthreads();
    #pragma unroll
    for (int j = 0; j < 16; j++) {
      int idx = tid + j * 256;
      int r = idx >> 6, c = idx & 63;
      T[(size_t)(n0 + r) * 512 + k0 + c] = tile[c * 72 + r];
    }
  } else {
    int local = bid - 672;
    const float* src = (local < ncast) ? kwf : vwf;
    unsigned short* dst = (local < ncast) ? kbf : vbf;
    size_t off = (size_t)((local < ncast) ? local : local - ncast) * 8192;
    #pragma unroll
    for (int i = 0; i < 8; i++) {
      size_t idx = off + ((size_t)i * 256 + tid) * 4;
      float4 v = *(const float4*)&src[idx];
      uint2 pk;
      pk.x = (unsigned)f2b(v.x) | ((unsigned)f2b(v.y) << 16);
      pk.y = (unsigned)f2b(v.z) | ((unsigned)f2b(v.w) << 16);
      *(uint2*)&dst[idx] = pk;
    }
  }
}

// ---------------- K2: big projections + sentence attention -----------------
// [0,1024): proj<0>; [1024,2048): proj<1>; [2048,2560): sent_attn.
__global__ __launch_bounds__(256)
void megaP_glds(const unsigned short* __restrict__ kbf,
                const unsigned short* __restrict__ vbf,
                const unsigned short* __restrict__ WkT, const float* __restrict__ b_kw,
                const unsigned short* __restrict__ WvT, const float* __restrict__ b_vw,
                __hip_bfloat16* kw_ws, __hip_bfloat16* vwT_ws,
                const float* __restrict__ qs, const float* __restrict__ ks,
                const float* __restrict__ vs, float* attn_s, float* ctx_s)
{
  __shared__ __attribute__((aligned(16))) unsigned short sm[16384];
  const int bid = blockIdx.x, tid = threadIdx.x;
  if (bid < 1024) {
    proj_glds<0>(sm, kbf, WkT, b_kw, kw_ws, bid, tid);
  } else if (bid < 2048) {
    proj_glds<1>(sm, vbf, WvT, b_vw, vwT_ws, bid - 1024, tid);
  } else {
    sent_body((float*)sm, qs, ks, vs, attn_s, ctx_s, bid - 2048, tid);
  }
}

__global__ __launch_bounds__(256)
void megaP_reg(const float* __restrict__ k_w, const float* __restrict__ v_w,
               const unsigned short* __restrict__ WkT, const float* __restrict__ b_kw,
               const unsigned short* __restrict__ WvT, const float* __restrict__ b_vw,
               __hip_bfloat16* kw_ws, __hip_bfloat16* vwT_ws,
               const float* __restrict__ qs, const float* __restrict__ ks,
               const float* __restrict__ vs, float* attn_s, float* ctx_s)
{
  __shared__ __attribute__((aligned(16))) unsigned short sm[16384];
  const int bid = blockIdx.x, tid = threadIdx.x;
  if (bid < 1024) {
    proj_reg<0>(sm, k_w, WkT, b_kw, kw_ws, bid, tid);
  } else if (bid < 2048) {
    proj_reg<1>(sm, v_w, WvT, b_vw, vwT_ws, bid - 1024, tid);
  } else {
    sent_body((float*)sm, qs, ks, vs, attn_s, ctx_s, bid - 2048, tid);
  }
}

// ---------------- K3: token attention + fc1 GEMM ---------------------------
__global__ __launch_bounds__(256, 2)
void megaB(const float* __restrict__ qw,
           const __hip_bfloat16* __restrict__ kw, const __hip_bfloat16* __restrict__ vwT,
           const float* __restrict__ attn_s, float* part0, float* part1,
           const float* __restrict__ ctxs,
           const float* __restrict__ W_fc1, const float* __restrict__ b_fc1,
           float* ctxsf)
{
  __shared__ __attribute__((aligned(16))) unsigned short sm[32768];
  const int bid = blockIdx.x, tid = threadIdx.x;
  if (bid < 512) {
    tok_body(sm, qw, kw, vwT, attn_s, part0, part1, bid, tid);
  } else {
    int local = bid - 512;
    sgemm_body<0>(sm, ctxs, nullptr, nullptr, W_fc1, b_fc1, ctxsf, 1.f,
                  (local & 31) * 64, (local >> 5) * 64, 512, tid);
  }
}

// ---------------- K4: final combine GEMM -----------------------------------
__global__ __launch_bounds__(256)
void final_gemm(const float* __restrict__ ctxsf,
                const float* __restrict__ p0, const float* __restrict__ p1,
                const float* __restrict__ W, const float* __restrict__ bias,
                float* out)
{
  __shared__ __attribute__((aligned(16))) unsigned short sm[16384];
  sgemm_body<1>(sm, ctxsf, p0, p1, W, bias, out, 1.f,
                blockIdx.x * 64, blockIdx.y * 64, 1024, threadIdx.x);
}

extern "C" void kernel_launch(void* const* d_in, const int* in_sizes, int n_in,
                              void* d_out, int out_size, void* d_ws, size_t ws_size,
                              hipStream_t stream)
{
  (void)in_sizes; (void)n_in; (void)out_size;
  const float* q    = (const float*)d_in[0];
  const float* k_w  = (const float*)d_in[1];
  const float* v_w  = (const float*)d_in[2];
  const float* k_s  = (const float*)d_in[3];
  const float* v_s  = (const float*)d_in[4];
  const float* W_qs = (const float*)d_in[5];  const float* b_qs = (const float*)d_in[6];
  const float* W_ks = (const float*)d_in[7];  const float* b_ks = (const float*)d_in[8];
  const float* W_vs = (const float*)d_in[9];  const float* b_vs = (const float*)d_in[10];
  const float* W_qw = (const float*)d_in[11]; const float* b_qw = (const float*)d_in[12];
  const float* W_kw = (const float*)d_in[13]; const float* b_kw = (const float*)d_in[14];
  const float* W_vw = (const float*)d_in[15]; const float* b_vw = (const float*)d_in[16];
  const float* W_fc1= (const float*)d_in[17]; const float* b_fc1= (const float*)d_in[18];
  const float* W_fc = (const float*)d_in[19]; const float* b_fc = (const float*)d_in[20];
  float* out = (float*)d_out;

  char* ws = (char*)d_ws;
  const size_t MB = 1ull << 20;
  const size_t KB = 1ull << 10;
  float* qs_ws    = (float*)(ws + 0 * MB);       // [b,h,512,64] 4 MB (dead after sent_attn)
  float* qw_ws    = (float*)(ws + 4 * MB);       // [b,h,512,64] 4 MB
  float* ks_ws    = (float*)(ws + 8 * MB);       // [b,h,32,64] 256 KB
  unsigned short* WkT = (unsigned short*)(ws + 8 * MB + 512 * KB);  // 512 KB
  float* vs_ws    = (float*)(ws + 9 * MB);       // [b,h,32,64] 256 KB
  unsigned short* WvT = (unsigned short*)(ws + 9 * MB + 512 * KB);  // 512 KB
  float* attns_ws = (float*)(ws + 10 * MB);      // [b,h,512,32] 2 MB
  float* ctxs_ws  = (float*)(ws + 12 * MB);      // [b,512,512] 4 MB (read by fc1 in megaB)
  float* ctxsf_ws = (float*)(ws + 16 * MB);      // [b,512,512] 4 MB
  float* part1    = (float*)(ws + 20 * MB);      // [b,512,512] 4 MB
  __hip_bfloat16* kw_ws  = (__hip_bfloat16*)(ws + 24 * MB);  // [b,h,32,256,64] 32 MB
  __hip_bfloat16* vwT_ws = (__hip_bfloat16*)(ws + 56 * MB);  // [b,h,32,64,256] 32 MB
  unsigned short* kbf = (unsigned short*)(ws + 88 * MB);     // [32768][512] bf16 32 MB
  unsigned short* vbf = (unsigned short*)(ws + 120 * MB);    // 32 MB
  float* part0    = (float*)(ws + 0 * MB);       // over qs_ws (dead by megaB)

  const bool use_glds = (ws_size >= 152ull * MB);
  const int ncast = use_glds ? 2048 : 0;

  dim3 blk(256);
  // K1: small projections + weight transpose-casts + A bf16 casts (independent)
  megaQ<<<dim3(672 + 2 * ncast), blk, 0, stream>>>(
      q, k_s, v_s, W_qs, b_qs, W_qw, b_qw, W_ks, b_ks, W_vs, b_vs,
      k_w, v_w, kbf, vbf, W_kw, WkT, W_vw, WvT,
      qs_ws, qw_ws, ks_ws, vs_ws, ncast);
  // K2: big projections + sentence attention
  if (use_glds) {
    megaP_glds<<<dim3(2560), blk, 0, stream>>>(
        kbf, vbf, WkT, b_kw, WvT, b_vw, kw_ws, vwT_ws,
        qs_ws, ks_ws, vs_ws, attns_ws, ctxs_ws);
  } else {
    megaP_reg<<<dim3(2560), blk, 0, stream>>>(
        k_w, v_w, WkT, b_kw, WvT, b_vw, kw_ws, vwT_ws,
        qs_ws, ks_ws, vs_ws, attns_ws, ctxs_ws);
  }
  // K3: token attention (512 blocks) + fc1 GEMM (256 blocks)
  megaB<<<dim3(768), blk, 0, stream>>>(
      qw_ws, kw_ws, vwT_ws, attns_ws, part0, part1,
      ctxs_ws, W_fc1, b_fc1, ctxsf_ws);
  // K4: final combine: concat([ctx_s_fc1, part0+part1]) @ W_fc + b_fc
  final_gemm<<<dim3(32, 8), blk, 0, stream>>>(ctxsf_ws, part0, part1, W_fc, b_fc, out);
}